// Round 1
// baseline (493.590 us; speedup 1.0000x reference)
//
#include <hip/hip_runtime.h>

#define NN 20000
#define EE 20000

// workspace layout (floats)
#define WS_AGG 0
#define WS_NUM (NN*64)
#define WS_CNT (NN*67)
#define WS_TOTAL (NN*68)

// shared-memory offsets (floats) inside sm[]
#define OFF_G   0       // g = e2, [64][32] i-major        (2048)
#define OFF_W   2048    // Ws1 chunk [32][128] / e1 / t1   (4096)
#define OFF_P   6144    // p tile [32][32]                 (1024)
#define OFF_IN  7168    // s_in [32][129] / ef+v later     (4128)
#define SM_FLOATS 11296

__device__ __forceinline__ float siluf(float x) {
    return x * (1.0f / (1.0f + __expf(-x)));
}

__global__ __launch_bounds__(256, 2)
void egcl_edge_kernel(const float* __restrict__ h, const float* __restrict__ coord,
                      const int* __restrict__ ei,
                      const float* __restrict__ We1, const float* __restrict__ be1,
                      const float* __restrict__ We2, const float* __restrict__ be2,
                      const float* __restrict__ Ws1, const float* __restrict__ bs1,
                      const float* __restrict__ Ws2, const float* __restrict__ bs2,
                      const float* __restrict__ Wc1, const float* __restrict__ bc1,
                      const float* __restrict__ Wc2,
                      float* __restrict__ ws)
{
    __shared__ __attribute__((aligned(16))) float sm[SM_FLOATS];
    __shared__ int s_row[32], s_col[32];
    __shared__ float s_cd[96], s_rad[32];

    const int t = threadIdx.x;
    const int e0 = blockIdx.x * 32;

    if (t < 32) {
        const int r = ei[e0 + t], c = ei[EE + e0 + t];
        s_row[t] = r; s_col[t] = c;
        const float dx = coord[r*3+0] - coord[c*3+0];
        const float dy = coord[r*3+1] - coord[c*3+1];
        const float dz = coord[r*3+2] - coord[c*3+2];
        s_cd[t] = dx; s_cd[32+t] = dy; s_cd[64+t] = dz;
        s_rad[t] = dx*dx + dy*dy + dz*dz;
    }
    __syncthreads();

    // gather: s_in[e][129] = [h[row] (64), h[col] (64), radial]
    {
        const int e = t >> 3, seg = t & 7;
        const int r = s_row[e], c = s_col[e];
        float* din = &sm[OFF_IN + e*129];
        #pragma unroll
        for (int u = 0; u < 8; ++u) din[seg*8 + u] = h[r*64 + seg*8 + u];
        #pragma unroll
        for (int u = 0; u < 8; ++u) din[64 + seg*8 + u] = h[c*64 + seg*8 + u];
        if (seg == 0) din[128] = s_rad[e];
    }
    __syncthreads();

    // e1 = silu(in @ We1 + be1) -> sm[OFF_W + o*32 + e]
    {
        const int e = t & 31, og = t >> 5;
        float acc[8];
        #pragma unroll
        for (int u = 0; u < 8; ++u) acc[u] = be1[og*8 + u];
        const float* din = &sm[OFF_IN + e*129];
        for (int q = 0; q < 129; ++q) {
            const float x = din[q];
            const float* wr = &We1[q*64 + og*8];
            #pragma unroll
            for (int u = 0; u < 8; ++u) acc[u] = fmaf(x, wr[u], acc[u]);
        }
        #pragma unroll
        for (int u = 0; u < 8; ++u) sm[OFF_W + (og*8+u)*32 + e] = siluf(acc[u]);
    }
    __syncthreads();

    // g = e2 = silu(e1 @ We2 + be2) -> sm[OFF_G + o*32 + e]
    {
        const int e = t & 31, og = t >> 5;
        float acc[8];
        #pragma unroll
        for (int u = 0; u < 8; ++u) acc[u] = be2[og*8 + u];
        for (int q = 0; q < 64; ++q) {
            const float x = sm[OFF_W + q*32 + e];
            const float* wr = &We2[q*64 + og*8];
            #pragma unroll
            for (int u = 0; u < 8; ++u) acc[u] = fmaf(x, wr[u], acc[u]);
        }
        #pragma unroll
        for (int u = 0; u < 8; ++u) sm[OFF_G + (og*8+u)*32 + e] = siluf(acc[u]);
    }
    __syncthreads();

    // SO3 bilinear as tiled GEMM: C[32e][128k] = sum_r p[e][r]*Ws1[r][k]
    // p[e][r=64i+j] = g[i][e]*g[j][e]  (the x64 scale applied at the end)
    float acc[4][4];
    #pragma unroll
    for (int a = 0; a < 4; ++a)
        #pragma unroll
        for (int b = 0; b < 4; ++b) acc[a][b] = 0.0f;
    const int eg = t & 7, kg = t >> 3;   // C sub-tile: e in [eg*4,+4), k in [kg*4,+4)

    for (int ch = 0; ch < 128; ++ch) {
        const int i = ch >> 1, jb = (ch & 1) * 32;
        // stage Ws1 rows [i*64+jb, +32): 4096 contiguous floats -> OFF_W
        {
            const float* src = &Ws1[(i*64 + jb)*128];
            #pragma unroll
            for (int it = 0; it < 4; ++it) {
                const int idx = (it*256 + t)*4;
                *(float4*)&sm[OFF_W + idx] = *(const float4*)&src[idx];
            }
        }
        // p tile
        {
            const int e = t & 31, rg = t >> 5;
            const float gi = sm[OFF_G + i*32 + e];
            #pragma unroll
            for (int u = 0; u < 4; ++u) {
                const int rr = rg*4 + u;
                sm[OFF_P + rr*32 + e] = gi * sm[OFF_G + (jb+rr)*32 + e];
            }
        }
        __syncthreads();
        #pragma unroll 8
        for (int rr = 0; rr < 32; ++rr) {
            const float4 a4 = *(const float4*)&sm[OFF_P + rr*32 + eg*4];
            const float4 b4 = *(const float4*)&sm[OFF_W + rr*128 + kg*4];
            const float av[4] = {a4.x, a4.y, a4.z, a4.w};
            const float bv[4] = {b4.x, b4.y, b4.z, b4.w};
            #pragma unroll
            for (int a = 0; a < 4; ++a)
                #pragma unroll
                for (int b = 0; b < 4; ++b)
                    acc[a][b] = fmaf(av[a], bv[b], acc[a][b]);
        }
        __syncthreads();
    }

    // t1[k][e] = relu(64*acc + bs1[k]) -> OFF_W region (GEMM done, safe)
    {
        #pragma unroll
        for (int b = 0; b < 4; ++b) {
            const int k = kg*4 + b;
            const float bk = bs1[k];
            #pragma unroll
            for (int a = 0; a < 4; ++a) {
                sm[OFF_W + k*32 + eg*4 + a] = fmaxf(fmaf(64.0f, acc[a][b], bk), 0.0f);
            }
        }
    }
    __syncthreads();

    // edge_feat = t1 @ Ws2 + bs2 -> ef[o][e] at OFF_IN
    {
        const int e = t & 31, og = t >> 5;
        float acc2[8];
        #pragma unroll
        for (int u = 0; u < 8; ++u) acc2[u] = bs2[og*8 + u];
        for (int k = 0; k < 128; ++k) {
            const float x = sm[OFF_W + k*32 + e];
            const float* wr = &Ws2[k*64 + og*8];
            #pragma unroll
            for (int u = 0; u < 8; ++u) acc2[u] = fmaf(x, wr[u], acc2[u]);
        }
        #pragma unroll
        for (int u = 0; u < 8; ++u) sm[OFF_IN + (og*8+u)*32 + e] = acc2[u];
    }
    __syncthreads();

    // coord hidden: v[f][e] = silu(ef @ Wc1 + bc1) at OFF_IN+2048
    {
        const int e = t & 31, og = t >> 5;
        float acc3[8];
        #pragma unroll
        for (int u = 0; u < 8; ++u) acc3[u] = bc1[og*8 + u];
        for (int q = 0; q < 64; ++q) {
            const float x = sm[OFF_IN + q*32 + e];
            const float* wr = &Wc1[q*64 + og*8];
            #pragma unroll
            for (int u = 0; u < 8; ++u) acc3[u] = fmaf(x, wr[u], acc3[u]);
        }
        #pragma unroll
        for (int u = 0; u < 8; ++u) sm[OFF_IN + 2048 + (og*8+u)*32 + e] = siluf(acc3[u]);
    }
    __syncthreads();

    // coord weight + scatter num/cnt
    if (t < 32) {
        float cw = 0.0f;
        for (int f = 0; f < 64; ++f) cw = fmaf(sm[OFF_IN + 2048 + f*32 + t], Wc2[f], cw);
        const int r = s_row[t];
        atomicAdd(&ws[WS_NUM + r*3 + 0], s_cd[t]    * cw);
        atomicAdd(&ws[WS_NUM + r*3 + 1], s_cd[32+t] * cw);
        atomicAdd(&ws[WS_NUM + r*3 + 2], s_cd[64+t] * cw);
        atomicAdd(&ws[WS_CNT + r], 1.0f);
    }
    // scatter agg (edge_feat sums per row)
    {
        const int e = t & 31, og = t >> 5;
        const int r = s_row[e];
        #pragma unroll
        for (int u = 0; u < 8; ++u) {
            const int o = og*8 + u;
            atomicAdd(&ws[WS_AGG + r*64 + o], sm[OFF_IN + o*32 + e]);
        }
    }
}

__global__ __launch_bounds__(256, 2)
void egcl_node_kernel(const float* __restrict__ h, const float* __restrict__ coord,
                      const int* __restrict__ ei,
                      const float* __restrict__ Wn1, const float* __restrict__ bn1,
                      const float* __restrict__ Wn2, const float* __restrict__ bn2,
                      const float* __restrict__ ws, float* __restrict__ out)
{
    __shared__ float s_m[131*32];   // m = [h(64), rel(3), agg(64)] q-major
    __shared__ float s_z[64*32];
    const int t = threadIdx.x;
    const int n0 = blockIdx.x * 32;

    {
        const int n = t >> 3, seg = t & 7;
        const float* hp = &h[(n0+n)*64 + seg*8];
        #pragma unroll
        for (int u = 0; u < 8; ++u) s_m[(seg*8+u)*32 + n] = hp[u];
        const float* ap = &ws[WS_AGG + (n0+n)*64 + seg*8];
        #pragma unroll
        for (int u = 0; u < 8; ++u) s_m[(67+seg*8+u)*32 + n] = ap[u];
    }
    if (t < 32) {
        const int n = n0 + t;
        const int r = ei[n], c = ei[EE + n];   // rel for node n comes from edge n
        const float dx = coord[r*3+0] - coord[c*3+0];
        const float dy = coord[r*3+1] - coord[c*3+1];
        const float dz = coord[r*3+2] - coord[c*3+2];
        const float inv = 1.0f / (sqrtf(dx*dx + dy*dy + dz*dz) + 1e-8f);
        s_m[64*32 + t] = dx*inv;
        s_m[65*32 + t] = dy*inv;
        s_m[66*32 + t] = dz*inv;
        const float cnt = fmaxf(ws[WS_CNT + n], 1.0f);
        out[NN*67 + n*3 + 0] = coord[n*3+0] + ws[WS_NUM + n*3 + 0] / cnt;
        out[NN*67 + n*3 + 1] = coord[n*3+1] + ws[WS_NUM + n*3 + 1] / cnt;
        out[NN*67 + n*3 + 2] = coord[n*3+2] + ws[WS_NUM + n*3 + 2] / cnt;
    }
    __syncthreads();

    // z = silu(m @ Wn1 + bn1)
    {
        const int n = t & 31, og = t >> 5;
        float acc[8];
        #pragma unroll
        for (int u = 0; u < 8; ++u) acc[u] = bn1[og*8 + u];
        for (int q = 0; q < 131; ++q) {
            const float x = s_m[q*32 + n];
            const float* wr = &Wn1[q*64 + og*8];
            #pragma unroll
            for (int u = 0; u < 8; ++u) acc[u] = fmaf(x, wr[u], acc[u]);
        }
        #pragma unroll
        for (int u = 0; u < 8; ++u) s_z[(og*8+u)*32 + n] = siluf(acc[u]);
    }
    __syncthreads();

    // h_out = h_pos + z @ Wn2 + bn2   (h_pos == m[0:67])
    {
        const int n = t & 31, og = t >> 5;
        for (int o = og; o < 67; o += 8) {
            float a = s_m[o*32 + n] + bn2[o];
            for (int k = 0; k < 64; ++k)
                a = fmaf(s_z[k*32 + n], Wn2[k*67 + o], a);
            out[(n0 + n)*67 + o] = a;
        }
    }
}

extern "C" void kernel_launch(void* const* d_in, const int* in_sizes, int n_in,
                              void* d_out, int out_size, void* d_ws, size_t ws_size,
                              hipStream_t stream)
{
    (void)in_sizes; (void)n_in; (void)out_size; (void)ws_size;
    const float* h     = (const float*)d_in[0];
    const float* coord = (const float*)d_in[1];
    const int*   ei    = (const int*)d_in[2];
    const float* We1   = (const float*)d_in[3];
    const float* be1   = (const float*)d_in[4];
    const float* We2   = (const float*)d_in[5];
    const float* be2   = (const float*)d_in[6];
    const float* Ws1   = (const float*)d_in[7];
    const float* bs1   = (const float*)d_in[8];
    const float* Ws2   = (const float*)d_in[9];
    const float* bs2   = (const float*)d_in[10];
    const float* Wc1   = (const float*)d_in[11];
    const float* bc1   = (const float*)d_in[12];
    const float* Wc2   = (const float*)d_in[13];
    const float* Wn1   = (const float*)d_in[14];
    const float* bn1   = (const float*)d_in[15];
    const float* Wn2   = (const float*)d_in[16];
    const float* bn2   = (const float*)d_in[17];
    float* ws  = (float*)d_ws;
    float* out = (float*)d_out;

    hipMemsetAsync(d_ws, 0, (size_t)WS_TOTAL * sizeof(float), stream);
    egcl_edge_kernel<<<EE/32, 256, 0, stream>>>(h, coord, ei, We1, be1, We2, be2,
                                                Ws1, bs1, Ws2, bs2, Wc1, bc1, Wc2, ws);
    egcl_node_kernel<<<NN/32, 256, 0, stream>>>(h, coord, ei, Wn1, bn1, Wn2, bn2, ws, out);
}

// Round 2
// 223.141 us; speedup vs baseline: 2.2120x; 2.2120x over previous
//
#include <hip/hip_runtime.h>

#define NN 20000
#define EE 20000

typedef __attribute__((ext_vector_type(8))) short short8;
typedef __attribute__((ext_vector_type(4))) float f32x4;

// workspace layout (floats)
#define WS_AGG 0
#define WS_NUM (NN*64)
#define WS_CNT (NN*67)
#define WS_TOTAL (NN*68)
#define WS1S_ELEMS (4096*128)   // bf16 elems of swizzled 64*Ws1 (1 MB)

// LDS float offsets
#define OFF_IN  0      // s_in [32][129] (4128), later t1 [128 cols][33] (4224)
#define OFF_G   4224   // g f32 [64 feat][32 edge] (2048)
#define OFF_GBF 6272   // g bf16, swizzled, 2048 halves = 1024 floats
#define OFF_E1  7296   // e1 [64][32] (2048), later v [64][32]
#define SM_FLOATS 9344 // ~37.4 KB

__device__ __forceinline__ float siluf(float x) {
    return x * (1.0f / (1.0f + __expf(-x)));
}
__device__ __forceinline__ unsigned short f2bf(float f) {
    union { float f; unsigned u; } v; v.f = f;
    return (unsigned short)((v.u + 0x7FFF + ((v.u >> 16) & 1)) >> 16);
}

// Pre-swizzle: out[((s*8+tn)*64 + l)*8 + u] = bf16(64*Ws1[(s*32 + 8*(l>>4) + u)][tn*16 + (l&15)])
// (s = K-step of 32 rows, tn = 16-col tile, l = lane, u = elem slot)
__global__ void swz_ws1(const float* __restrict__ Ws1, unsigned short* __restrict__ out) {
    const int tid = blockIdx.x * 256 + threadIdx.x;   // 65536 threads
    const int l = tid & 63, fid = tid >> 6;
    const int s = fid >> 3, tn = fid & 7;
    const int krow = s * 32 + 8 * (l >> 4);
    const int ncol = tn * 16 + (l & 15);
    short8 frag;
    #pragma unroll
    for (int u = 0; u < 8; ++u)
        frag[u] = (short)f2bf(64.0f * Ws1[(krow + u) * 128 + ncol]);
    *(short8*)&out[(size_t)tid * 8] = frag;
}

__global__ __launch_bounds__(256, 3)
void egcl_edge_kernel(const float* __restrict__ h, const float* __restrict__ coord,
                      const int* __restrict__ ei,
                      const float* __restrict__ We1, const float* __restrict__ be1,
                      const float* __restrict__ We2, const float* __restrict__ be2,
                      const unsigned short* __restrict__ Ws1s, const float* __restrict__ bs1,
                      const float* __restrict__ Ws2, const float* __restrict__ bs2,
                      const float* __restrict__ Wc1, const float* __restrict__ bc1,
                      const float* __restrict__ Wc2,
                      float* __restrict__ ws)
{
    __shared__ __attribute__((aligned(16))) float sm[SM_FLOATS];
    __shared__ int s_row[32], s_col[32];
    __shared__ float s_cd[96], s_rad[32];

    const int t = threadIdx.x;
    const int e0 = blockIdx.x * 32;

    if (t < 32) {
        const int r = ei[e0 + t], c = ei[EE + e0 + t];
        s_row[t] = r; s_col[t] = c;
        const float dx = coord[r*3+0] - coord[c*3+0];
        const float dy = coord[r*3+1] - coord[c*3+1];
        const float dz = coord[r*3+2] - coord[c*3+2];
        s_cd[t] = dx; s_cd[32+t] = dy; s_cd[64+t] = dz;
        s_rad[t] = dx*dx + dy*dy + dz*dz;
    }
    __syncthreads();

    // gather: s_in[e][129] = [h[row], h[col], radial]
    {
        const int e = t >> 3, seg = t & 7;
        const int r = s_row[e], c = s_col[e];
        float* din = &sm[OFF_IN + e*129];
        #pragma unroll
        for (int u = 0; u < 8; ++u) din[seg*8 + u] = h[r*64 + seg*8 + u];
        #pragma unroll
        for (int u = 0; u < 8; ++u) din[64 + seg*8 + u] = h[c*64 + seg*8 + u];
        if (seg == 0) din[128] = s_rad[e];
    }
    __syncthreads();

    // e1 = silu(in @ We1 + be1) -> OFF_E1 [feat][edge]
    {
        const int e = t & 31, og = t >> 5;
        float acc[8];
        #pragma unroll
        for (int u = 0; u < 8; ++u) acc[u] = be1[og*8 + u];
        const float* din = &sm[OFF_IN + e*129];
        for (int q = 0; q < 129; ++q) {
            const float x = din[q];
            const float* wr = &We1[q*64 + og*8];
            #pragma unroll
            for (int u = 0; u < 8; ++u) acc[u] = fmaf(x, wr[u], acc[u]);
        }
        #pragma unroll
        for (int u = 0; u < 8; ++u) sm[OFF_E1 + (og*8+u)*32 + e] = siluf(acc[u]);
    }
    __syncthreads();

    // g = silu(e1 @ We2 + be2) -> f32 at OFF_G [feat][edge] + bf16 swizzled at OFF_GBF [edge][feat]
    {
        const int e = t & 31, og = t >> 5;
        float acc[8];
        #pragma unroll
        for (int u = 0; u < 8; ++u) acc[u] = be2[og*8 + u];
        for (int q = 0; q < 64; ++q) {
            const float x = sm[OFF_E1 + q*32 + e];
            const float* wr = &We2[q*64 + og*8];
            #pragma unroll
            for (int u = 0; u < 8; ++u) acc[u] = fmaf(x, wr[u], acc[u]);
        }
        short8 frag;
        #pragma unroll
        for (int u = 0; u < 8; ++u) {
            const float s = siluf(acc[u]);
            sm[OFF_G + (og*8+u)*32 + e] = s;
            frag[u] = (short)f2bf(s);
        }
        *(short8*)((char*)sm + OFF_GBF*4 + e*128 + ((og ^ (e & 7)) * 16)) = frag;
    }
    __syncthreads();

    // ---- SO3 GEMM via MFMA: acc[e,k] = sum_i g_f32[e,i] * (g_bf16[e,:] @ 64*Ws1_i[:,k])
    const int l = t & 63, w = t >> 6;
    const int wm = w & 1, wn = w >> 1;        // wave tile: edges [wm*16,+16), cols [wn*64,+64)
    const int erow = wm*16 + (l & 15);
    const int kg = l >> 4;                     // lane k-group
    const short8 A0 = *(const short8*)((const char*)sm + OFF_GBF*4 + erow*128 + (((0*4 + kg) ^ (erow & 7)) * 16));
    const short8 A1 = *(const short8*)((const char*)sm + OFF_GBF*4 + erow*128 + (((4   + kg) ^ (erow & 7)) * 16));

    float accv[4][4];
    #pragma unroll
    for (int nt = 0; nt < 4; ++nt)
        #pragma unroll
        for (int r = 0; r < 4; ++r) accv[nt][r] = 0.0f;

    const short8* Bp = (const short8*)Ws1s;
    const int tnb = wn * 4;

#define LOADB(buf, ii) { \
    _Pragma("unroll") \
    for (int q = 0; q < 8; ++q) \
        buf[q] = Bp[(((ii)*2 + (q >> 2)) * 8 + tnb + (q & 3)) * 64 + l]; \
}
#define COMPUTE(buf, ii) { \
    f32x4 ci[4]; \
    _Pragma("unroll") \
    for (int nt = 0; nt < 4; ++nt) \
        ci[nt] = __builtin_amdgcn_mfma_f32_16x16x32_bf16(A0, buf[nt], (f32x4){0.f,0.f,0.f,0.f}, 0, 0, 0); \
    _Pragma("unroll") \
    for (int nt = 0; nt < 4; ++nt) \
        ci[nt] = __builtin_amdgcn_mfma_f32_16x16x32_bf16(A1, buf[4+nt], ci[nt], 0, 0, 0); \
    const f32x4 g4 = *(const f32x4*)&sm[OFF_G + (ii)*32 + wm*16 + (kg << 2)]; \
    _Pragma("unroll") \
    for (int nt = 0; nt < 4; ++nt) \
        _Pragma("unroll") \
        for (int r = 0; r < 4; ++r) accv[nt][r] = fmaf(g4[r], ci[nt][r], accv[nt][r]); \
}

    {
        short8 bufA[8], bufB[8];
        LOADB(bufA, 0);
        for (int i = 0; i < 64; i += 2) {
            LOADB(bufB, i + 1);
            COMPUTE(bufA, i);
            if (i + 2 < 64) LOADB(bufA, i + 2);
            COMPUTE(bufB, i + 1);
        }
    }
#undef LOADB
#undef COMPUTE

    // t1 = relu(acc + bs1) -> OFF_IN, [col][33] padded
    #pragma unroll
    for (int nt = 0; nt < 4; ++nt) {
        const int col = wn*64 + nt*16 + (l & 15);
        const float bk = bs1[col];
        #pragma unroll
        for (int r = 0; r < 4; ++r) {
            const int row = wm*16 + (kg << 2) + r;
            sm[OFF_IN + col*33 + row] = fmaxf(accv[nt][r] + bk, 0.0f);
        }
    }
    __syncthreads();

    // edge_feat = t1 @ Ws2 + bs2 -> OFF_G [o][e]
    {
        const int e = t & 31, og = t >> 5;
        float a2[8];
        #pragma unroll
        for (int u = 0; u < 8; ++u) a2[u] = bs2[og*8 + u];
        for (int k = 0; k < 128; ++k) {
            const float x = sm[OFF_IN + k*33 + e];
            const float* wr = &Ws2[k*64 + og*8];
            #pragma unroll
            for (int u = 0; u < 8; ++u) a2[u] = fmaf(x, wr[u], a2[u]);
        }
        #pragma unroll
        for (int u = 0; u < 8; ++u) sm[OFF_G + (og*8+u)*32 + e] = a2[u];
    }
    __syncthreads();

    // v = silu(ef @ Wc1 + bc1) -> OFF_E1 [f][e]
    {
        const int e = t & 31, og = t >> 5;
        float a3[8];
        #pragma unroll
        for (int u = 0; u < 8; ++u) a3[u] = bc1[og*8 + u];
        for (int q = 0; q < 64; ++q) {
            const float x = sm[OFF_G + q*32 + e];
            const float* wr = &Wc1[q*64 + og*8];
            #pragma unroll
            for (int u = 0; u < 8; ++u) a3[u] = fmaf(x, wr[u], a3[u]);
        }
        #pragma unroll
        for (int u = 0; u < 8; ++u) sm[OFF_E1 + (og*8+u)*32 + e] = siluf(a3[u]);
    }
    __syncthreads();

    // coord weight + scatter num/cnt
    if (t < 32) {
        float cw = 0.0f;
        for (int f = 0; f < 64; ++f) cw = fmaf(sm[OFF_E1 + f*32 + t], Wc2[f], cw);
        const int r = s_row[t];
        atomicAdd(&ws[WS_NUM + r*3 + 0], s_cd[t]    * cw);
        atomicAdd(&ws[WS_NUM + r*3 + 1], s_cd[32+t] * cw);
        atomicAdd(&ws[WS_NUM + r*3 + 2], s_cd[64+t] * cw);
        atomicAdd(&ws[WS_CNT + r], 1.0f);
    }
    // scatter agg (edge_feat per row)
    {
        const int e = t & 31, og = t >> 5;
        const int r = s_row[e];
        #pragma unroll
        for (int u = 0; u < 8; ++u) {
            const int o = og*8 + u;
            atomicAdd(&ws[WS_AGG + r*64 + o], sm[OFF_G + o*32 + e]);
        }
    }
}

__global__ __launch_bounds__(256, 2)
void egcl_node_kernel(const float* __restrict__ h, const float* __restrict__ coord,
                      const int* __restrict__ ei,
                      const float* __restrict__ Wn1, const float* __restrict__ bn1,
                      const float* __restrict__ Wn2, const float* __restrict__ bn2,
                      const float* __restrict__ ws, float* __restrict__ out)
{
    __shared__ float s_m[131*32];
    __shared__ float s_z[64*32];
    const int t = threadIdx.x;
    const int n0 = blockIdx.x * 32;

    {
        const int n = t >> 3, seg = t & 7;
        const float* hp = &h[(n0+n)*64 + seg*8];
        #pragma unroll
        for (int u = 0; u < 8; ++u) s_m[(seg*8+u)*32 + n] = hp[u];
        const float* ap = &ws[WS_AGG + (n0+n)*64 + seg*8];
        #pragma unroll
        for (int u = 0; u < 8; ++u) s_m[(67+seg*8+u)*32 + n] = ap[u];
    }
    if (t < 32) {
        const int n = n0 + t;
        const int r = ei[n], c = ei[EE + n];
        const float dx = coord[r*3+0] - coord[c*3+0];
        const float dy = coord[r*3+1] - coord[c*3+1];
        const float dz = coord[r*3+2] - coord[c*3+2];
        const float inv = 1.0f / (sqrtf(dx*dx + dy*dy + dz*dz) + 1e-8f);
        s_m[64*32 + t] = dx*inv;
        s_m[65*32 + t] = dy*inv;
        s_m[66*32 + t] = dz*inv;
        const float cnt = fmaxf(ws[WS_CNT + n], 1.0f);
        out[NN*67 + n*3 + 0] = coord[n*3+0] + ws[WS_NUM + n*3 + 0] / cnt;
        out[NN*67 + n*3 + 1] = coord[n*3+1] + ws[WS_NUM + n*3 + 1] / cnt;
        out[NN*67 + n*3 + 2] = coord[n*3+2] + ws[WS_NUM + n*3 + 2] / cnt;
    }
    __syncthreads();

    {
        const int n = t & 31, og = t >> 5;
        float acc[8];
        #pragma unroll
        for (int u = 0; u < 8; ++u) acc[u] = bn1[og*8 + u];
        for (int q = 0; q < 131; ++q) {
            const float x = s_m[q*32 + n];
            const float* wr = &Wn1[q*64 + og*8];
            #pragma unroll
            for (int u = 0; u < 8; ++u) acc[u] = fmaf(x, wr[u], acc[u]);
        }
        #pragma unroll
        for (int u = 0; u < 8; ++u) s_z[(og*8+u)*32 + n] = siluf(acc[u]);
    }
    __syncthreads();

    {
        const int n = t & 31, og = t >> 5;
        for (int o = og; o < 67; o += 8) {
            float a = s_m[o*32 + n] + bn2[o];
            for (int k = 0; k < 64; ++k)
                a = fmaf(s_z[k*32 + n], Wn2[k*67 + o], a);
            out[(n0 + n)*67 + o] = a;
        }
    }
}

extern "C" void kernel_launch(void* const* d_in, const int* in_sizes, int n_in,
                              void* d_out, int out_size, void* d_ws, size_t ws_size,
                              hipStream_t stream)
{
    (void)in_sizes; (void)n_in; (void)out_size;
    const float* h     = (const float*)d_in[0];
    const float* coord = (const float*)d_in[1];
    const int*   ei    = (const int*)d_in[2];
    const float* We1   = (const float*)d_in[3];
    const float* be1   = (const float*)d_in[4];
    const float* We2   = (const float*)d_in[5];
    const float* be2   = (const float*)d_in[6];
    const float* Ws1   = (const float*)d_in[7];
    const float* bs1   = (const float*)d_in[8];
    const float* Ws2   = (const float*)d_in[9];
    const float* bs2   = (const float*)d_in[10];
    const float* Wc1   = (const float*)d_in[11];
    const float* bc1   = (const float*)d_in[12];
    const float* Wc2   = (const float*)d_in[13];
    const float* Wn1   = (const float*)d_in[14];
    const float* bn1   = (const float*)d_in[15];
    const float* Wn2   = (const float*)d_in[16];
    const float* bn2   = (const float*)d_in[17];
    float* ws  = (float*)d_ws;
    float* out = (float*)d_out;

    const size_t need = (size_t)WS_TOTAL * sizeof(float) + (size_t)WS1S_ELEMS * 2;
    unsigned short* ws1s = (ws_size >= need) ? (unsigned short*)(ws + WS_TOTAL)
                                             : (unsigned short*)d_out;  // node kernel rewrites d_out afterwards

    hipMemsetAsync(d_ws, 0, (size_t)WS_TOTAL * sizeof(float), stream);
    swz_ws1<<<256, 256, 0, stream>>>(Ws1, ws1s);
    egcl_edge_kernel<<<EE/32, 256, 0, stream>>>(h, coord, ei, We1, be1, We2, be2,
                                                ws1s, bs1, Ws2, bs2, Wc1, bc1, Wc2, ws);
    egcl_node_kernel<<<NN/32, 256, 0, stream>>>(h, coord, ei, Wn1, bn1, Wn2, bn2, ws, out);
}